// Round 1
// baseline (370.668 us; speedup 1.0000x reference)
//
#include <hip/hip_runtime.h>
#include <hip/hip_bf16.h>
#include <cstdint>

// SimpleGAT on MI355X. Round 7:
//   R6 @325us. gemm1 top @61us: MfmaUtil 19, VALUBusy 20, HBM 23%, Occ 26%,
//   0 bank conflicts -> no pipe saturated. Per-kt: 16 ds_read_b128 (192cy)
//   vs 24 MFMA (120cy) + ~40 VALU of fp32->bf16 split = LDS+VALU out-cost
//   the matrix pipe; 2 waves/SIMD can't hide it.
// Changes:
//   1. Block = 128 rows x 64 cols (grid 157 x N/64). Each wave: 2 row-frags
//      x 4 col-tiles -> 48 MFMA per 8 ds_read (3:1, was 1.5:1). LDS 16KB.
//      A register-prefetched one kt ahead (barrier drain covers latency).
//   2. A pre-split to hi/lo bf16 OUTSIDE the GEMMs: split_f32 pass for x,
//      agg1 epilogue emits h1e as split bf16 -> zero conversion VALU in the
//      GEMM inner loop. Same decomposition => numerics unchanged.
//   3. Layer-1 attn dots: 64-col blocks = half head -> atomicAdd into
//      zeroed as1/ad1 (pattern already used for layer 2).
//
// MFMA 16x16x32 bf16 layouts (verified R3-R5):
//   A: lane holds A[m=lane&15][k=(lane>>4)*8 + j], j=0..7
//   B: lane holds B[k=(lane>>4)*8 + j][n=lane&15]   (pre-swizzled contiguous)
//   C/D: col = lane&15, row = (lane>>4)*4 + reg

#define NNODES 20000
#define NEDGES 320000
#define ETOT   340000   // NEDGES + NNODES self loops
#define F1     512      // HEADS*HID
#define F2     256      // OUT_CH
#define HEADS  4

typedef __bf16 bf16;
typedef __attribute__((ext_vector_type(8))) __bf16 bf16x8;
typedef __attribute__((ext_vector_type(4))) float f32x4;

__device__ __forceinline__ float bflo(unsigned p) { return __uint_as_float(p << 16); }
__device__ __forceinline__ float bfhi(unsigned p) { return __uint_as_float(p & 0xffff0000u); }

__device__ __forceinline__ void gload_lds16(const void* g, void* l) {
    __builtin_amdgcn_global_load_lds(
        (const __attribute__((address_space(1))) void*)g,
        (__attribute__((address_space(3))) void*)l, 16, 0, 0);
}

// ---------------- CSR build ----------------
__global__ void deg_count(const int* __restrict__ ei, int* __restrict__ deg) {
    int e = blockIdx.x * blockDim.x + threadIdx.x;
    if (e >= ETOT) return;
    int dst = (e < NEDGES) ? ei[NEDGES + e] : (e - NEDGES);
    atomicAdd(&deg[dst], 1);
}

// 1024 threads, 20 elems each (20480 >= 20000); one block-scan.
__global__ void scan_deg(const int* __restrict__ deg, int* __restrict__ offs,
                         int* __restrict__ cur) {
    __shared__ int sums[1024];
    const int t = threadIdx.x;
    const int PER = 20;
    int base = t * PER;
    int local[PER];
    int run = 0;
#pragma unroll
    for (int j = 0; j < PER; j++) {
        int i = base + j;
        int v = (i < NNODES) ? deg[i] : 0;
        local[j] = run;
        run += v;
    }
    sums[t] = run;
    __syncthreads();
    for (int o = 1; o < 1024; o <<= 1) {
        int v = (t >= o) ? sums[t - o] : 0;
        __syncthreads();
        sums[t] += v;
        __syncthreads();
    }
    int texcl = (t == 0) ? 0 : sums[t - 1];
#pragma unroll
    for (int j = 0; j < PER; j++) {
        int i = base + j;
        if (i < NNODES) {
            int e = texcl + local[j];
            cur[i] = e;
            offs[i] = e;
        }
    }
    if (t == 1023) offs[NNODES] = sums[1023];
}

__global__ void fill_csr(const int* __restrict__ ei, int* __restrict__ cur,
                         int* __restrict__ csr_src, int* __restrict__ csr_eid) {
    int e = blockIdx.x * blockDim.x + threadIdx.x;
    if (e >= ETOT) return;
    int src, dst;
    if (e < NEDGES) { src = ei[e]; dst = ei[NEDGES + e]; }
    else            { src = dst = e - NEDGES; }
    int p = atomicAdd(&cur[dst], 1);
    csr_src[p] = src;
    csr_eid[p] = e;
}

// ---------------- W swizzle (fp32 -> hi/lo bf16 B-fragment order) ----------------
__global__ void swizzle_w(const float* __restrict__ W, bf16* __restrict__ Wh,
                          bf16* __restrict__ Wl, int K, int N) {
    int idx = blockIdx.x * blockDim.x + threadIdx.x;  // one thread per 8 elements
    int total = (K * N) >> 3;
    if (idx >= total) return;
    int lane = idx & 63;
    int tile = idx >> 6;            // kt*(N/16) + nt
    int NT = N >> 4;
    int kt = tile / NT, nt = tile - kt * NT;
    int krow = kt * 32 + (lane >> 4) * 8;
    int col  = nt * 16 + (lane & 15);
    union { bf16 b[8]; uint4 u; } hi, lo;
#pragma unroll
    for (int j = 0; j < 8; j++) {
        float w = W[(size_t)(krow + j) * N + col];
        bf16 h = (bf16)w;
        hi.b[j] = h;
        lo.b[j] = (bf16)(w - (float)h);
    }
    *(uint4*)(Wh + (size_t)idx * 8) = hi.u;
    *(uint4*)(Wl + (size_t)idx * 8) = lo.u;
}

// ---------------- fp32 -> split hi/lo bf16, row-major ----------------
__global__ void split_f32(const float* __restrict__ X, bf16* __restrict__ Xh,
                          bf16* __restrict__ Xl, int total8) {
    int i = blockIdx.x * blockDim.x + threadIdx.x;
    if (i >= total8) return;
    float v[8];
    *(float4*)(v)     = *(const float4*)(X + (size_t)i * 8);
    *(float4*)(v + 4) = *(const float4*)(X + (size_t)i * 8 + 4);
    union { bf16 b[8]; uint4 u; } h, l;
#pragma unroll
    for (int j = 0; j < 8; j++) {
        bf16 hh = (bf16)v[j];
        h.b[j] = hh;
        l.b[j] = (bf16)(v[j] - (float)hh);
    }
    *(uint4*)(Xh + (size_t)i * 8) = h.u;
    *(uint4*)(Xl + (size_t)i * 8) = l.u;
}

// ------- split-bf16 MFMA GEMM, LDS-staged B, fused attn-coef epilogue -------
// block = 4 waves; wave owns 32 rows (2 frags) x 64 cols (4 tiles).
// LDS per kt: [hi 4KB | lo 4KB]; double-buffered. A pre-split bf16, reg-prefetched.
template <int K, int N>
__global__ __launch_bounds__(256) void gemm_fused(const bf16* __restrict__ Ah,
                                                  const bf16* __restrict__ Al,
                                                  const bf16* __restrict__ Bh,
                                                  const bf16* __restrict__ Bl,
                                                  bf16* __restrict__ Cb,
                                                  const float* __restrict__ asrc,
                                                  const float* __restrict__ adst,
                                                  float* __restrict__ as_out,
                                                  float* __restrict__ ad_out, int M) {
    __shared__ __align__(16) char smem[2][8192];
    const int lane = threadIdx.x & 63;
    const int wave = threadIdx.x >> 6;
    const int row_base = blockIdx.x * 128 + wave * 32;
    const int colt0 = blockIdx.y * 4;   // 4 col-tiles of 16 = 64 cols
    constexpr int NT = N / 16;
    constexpr int NKT = K / 32;

    const char* hbase = (const char*)Bh + (size_t)colt0 * 1024;
    const char* lbase = (const char*)Bl + (size_t)colt0 * 1024;
    // stage 8KB (4KB hi + 4KB lo) for K-slice kt; each wave moves 2KB.
    auto stage = [&](int kt, int buf) {
        size_t kb = (size_t)kt * NT * 1024;
#pragma unroll
        for (int q = 0; q < 2; q++) {
            int off = wave * 2048 + q * 1024;
            const char* src = (off < 4096) ? (hbase + kb + off)
                                           : (lbase + kb + (off - 4096));
            gload_lds16(src + lane * 16, &smem[buf][off]);
        }
    };

    int arow0 = row_base + (lane & 15);
    int arow1 = arow0 + 16;
    if (arow0 >= M) arow0 = M - 1;      // clamp; stores are guarded
    if (arow1 >= M) arow1 = M - 1;
    const int ko = (lane >> 4) * 8;
    const bf16* pah0 = Ah + (size_t)arow0 * K + ko;
    const bf16* pal0 = Al + (size_t)arow0 * K + ko;
    const bf16* pah1 = Ah + (size_t)arow1 * K + ko;
    const bf16* pal1 = Al + (size_t)arow1 * K + ko;

    f32x4 acc0[4] = {}, acc1[4] = {};
    bf16x8 ah0 = *(const bf16x8*)pah0;
    bf16x8 al0 = *(const bf16x8*)pal0;
    bf16x8 ah1 = *(const bf16x8*)pah1;
    bf16x8 al1 = *(const bf16x8*)pal1;

    auto body = [&](const char* bb) {
#pragma unroll
        for (int c = 0; c < 4; c++) {
            bf16x8 bh = *(const bf16x8*)(bb + c * 1024 + lane * 16);
            bf16x8 bl = *(const bf16x8*)(bb + 4096 + c * 1024 + lane * 16);
            acc0[c] = __builtin_amdgcn_mfma_f32_16x16x32_bf16(ah0, bh, acc0[c], 0, 0, 0);
            acc1[c] = __builtin_amdgcn_mfma_f32_16x16x32_bf16(ah1, bh, acc1[c], 0, 0, 0);
            acc0[c] = __builtin_amdgcn_mfma_f32_16x16x32_bf16(ah0, bl, acc0[c], 0, 0, 0);
            acc1[c] = __builtin_amdgcn_mfma_f32_16x16x32_bf16(ah1, bl, acc1[c], 0, 0, 0);
            acc0[c] = __builtin_amdgcn_mfma_f32_16x16x32_bf16(al0, bh, acc0[c], 0, 0, 0);
            acc1[c] = __builtin_amdgcn_mfma_f32_16x16x32_bf16(al1, bh, acc1[c], 0, 0, 0);
        }
    };

    stage(0, 0);
    __syncthreads();
    for (int kt = 0; kt < NKT - 1; ++kt) {
        stage(kt + 1, (kt + 1) & 1);
        bf16x8 nah0 = *(const bf16x8*)(pah0 + (kt + 1) * 32);
        bf16x8 nal0 = *(const bf16x8*)(pal0 + (kt + 1) * 32);
        bf16x8 nah1 = *(const bf16x8*)(pah1 + (kt + 1) * 32);
        bf16x8 nal1 = *(const bf16x8*)(pal1 + (kt + 1) * 32);
        body(smem[kt & 1]);
        __syncthreads();
        ah0 = nah0; al0 = nal0; ah1 = nah1; al1 = nal1;
    }
    body(smem[(NKT - 1) & 1]);

    const int crow0 = row_base + (lane >> 4) * 4;  // frag0 rows; frag1 = +16
    const int col15 = lane & 15;
#pragma unroll
    for (int c = 0; c < 4; c++)
#pragma unroll
        for (int r = 0; r < 4; r++) {
            int r0 = crow0 + r, r1 = r0 + 16;
            int cc = (colt0 + c) * 16 + col15;
            if (r0 < M) Cb[(size_t)r0 * N + cc] = (bf16)acc0[c][r];
            if (r1 < M) Cb[(size_t)r1 * N + cc] = (bf16)acc1[c][r];
        }

    // fused attention coefficient dots (block's 64 cols = half head for N=512)
    float ss0[4] = {}, sd0[4] = {}, ss1[4] = {}, sd1[4] = {};
#pragma unroll
    for (int c = 0; c < 4; c++) {
        int cw = blockIdx.y * 64 + c * 16 + col15;   // global column
        float was = asrc[cw];                         // asrc laid out [H*128]/[256]
        float wad = adst[cw];
#pragma unroll
        for (int r = 0; r < 4; r++) {
            ss0[r] += acc0[c][r] * was; sd0[r] += acc0[c][r] * wad;
            ss1[r] += acc1[c][r] * was; sd1[r] += acc1[c][r] * wad;
        }
    }
#pragma unroll
    for (int o = 1; o < 16; o <<= 1)
#pragma unroll
        for (int r = 0; r < 4; r++) {
            ss0[r] += __shfl_xor(ss0[r], o); sd0[r] += __shfl_xor(sd0[r], o);
            ss1[r] += __shfl_xor(ss1[r], o); sd1[r] += __shfl_xor(sd1[r], o);
        }
    if (col15 == 0) {
        constexpr int HS = (N == 512) ? 4 : 1;       // head stride in as/ad
        const int head = (N == 512) ? (blockIdx.y >> 1) : 0;
#pragma unroll
        for (int r = 0; r < 4; r++) {
            int r0 = crow0 + r, r1 = r0 + 16;
            if (r0 < M) {
                atomicAdd(&as_out[r0 * HS + head], ss0[r]);
                atomicAdd(&ad_out[r0 * HS + head], sd0[r]);
            }
            if (r1 < M) {
                atomicAdd(&as_out[r1 * HS + head], ss1[r]);
                atomicAdd(&ad_out[r1 * HS + head], sd1[r]);
            }
        }
    }
}

// -------- layer 1 softmax + aggregate: ONE WAVE per node --------
__global__ __launch_bounds__(64) void agg1(const bf16* __restrict__ h1b,
                                           const float* __restrict__ as1,
                                           const float* __restrict__ ad1,
                                           const int* __restrict__ offs,
                                           const int* __restrict__ csr_src,
                                           const int* __restrict__ csr_eid,
                                           const float* __restrict__ b1,
                                           float* __restrict__ alpha1,
                                           bf16* __restrict__ h1eh,
                                           bf16* __restrict__ h1el) {
    const int n = blockIdx.x;
    const int lane = threadIdx.x;
    const int beg = offs[n];
    const int deg = offs[n + 1] - beg;

    __shared__ int   s_src[64];
    __shared__ float s_al[64][4];

    float4 ad4 = *(const float4*)(ad1 + n * 4);
    const float adn[4] = {ad4.x, ad4.y, ad4.z, ad4.w};

    float v0[4];
    int s0 = 0, e0 = 0;
    float mx[4] = {-3e38f, -3e38f, -3e38f, -3e38f};
    for (int idx = lane; idx < deg; idx += 64) {
        int s = csr_src[beg + idx];
        float4 a4 = *(const float4*)(as1 + s * 4);
        float v[4] = {a4.x + adn[0], a4.y + adn[1], a4.z + adn[2], a4.w + adn[3]};
#pragma unroll
        for (int h = 0; h < 4; h++) {
            v[h] = v[h] > 0.f ? v[h] : 0.2f * v[h];
            mx[h] = fmaxf(mx[h], v[h]);
        }
        if (idx == lane) {
            s0 = s; e0 = csr_eid[beg + idx];
#pragma unroll
            for (int h = 0; h < 4; h++) v0[h] = v[h];
        }
    }
#pragma unroll
    for (int o = 1; o < 64; o <<= 1)
#pragma unroll
        for (int h = 0; h < 4; h++) mx[h] = fmaxf(mx[h], __shfl_xor(mx[h], o));

    float ex0[4] = {0.f, 0.f, 0.f, 0.f};
    float ls[4] = {0.f, 0.f, 0.f, 0.f};
    if (lane < deg) {
#pragma unroll
        for (int h = 0; h < 4; h++) { ex0[h] = __expf(v0[h] - mx[h]); ls[h] = ex0[h]; }
    }
    for (int idx = lane + 64; idx < deg; idx += 64) {
        int s = csr_src[beg + idx];
        float4 a4 = *(const float4*)(as1 + s * 4);
        float v[4] = {a4.x + adn[0], a4.y + adn[1], a4.z + adn[2], a4.w + adn[3]};
#pragma unroll
        for (int h = 0; h < 4; h++) {
            v[h] = v[h] > 0.f ? v[h] : 0.2f * v[h];
            ls[h] += __expf(v[h] - mx[h]);
        }
    }
#pragma unroll
    for (int o = 1; o < 64; o <<= 1)
#pragma unroll
        for (int h = 0; h < 4; h++) ls[h] += __shfl_xor(ls[h], o);
    float rden[4];
#pragma unroll
    for (int h = 0; h < 4; h++) rden[h] = 1.f / ls[h];

    float acc[8] = {};
    const int myh = lane >> 4;
    for (int base = 0; base < deg; base += 64) {
        int idx = base + lane;
        if (idx < deg) {
            int s, e;
            float al[4];
            if (base == 0) {
                s = s0; e = e0;
#pragma unroll
                for (int h = 0; h < 4; h++) al[h] = ex0[h] * rden[h];
            } else {
                s = csr_src[beg + idx];
                e = csr_eid[beg + idx];
                float4 a4 = *(const float4*)(as1 + s * 4);
                float v[4] = {a4.x + adn[0], a4.y + adn[1], a4.z + adn[2], a4.w + adn[3]};
#pragma unroll
                for (int h = 0; h < 4; h++) {
                    v[h] = v[h] > 0.f ? v[h] : 0.2f * v[h];
                    al[h] = __expf(v[h] - mx[h]) * rden[h];
                }
            }
            s_src[lane] = s;
#pragma unroll
            for (int h = 0; h < 4; h++) s_al[lane][h] = al[h];
            *(float4*)(alpha1 + (size_t)e * 4) = make_float4(al[0], al[1], al[2], al[3]);
        }
        __syncthreads();
        int cnt = min(64, deg - base);
        for (int i = 0; i < cnt; i++) {
            int s = s_src[i];
            float a = s_al[i][myh];
            uint4 p = *(const uint4*)(h1b + (size_t)s * F1 + lane * 8);
            acc[0] += a * bflo(p.x); acc[1] += a * bfhi(p.x);
            acc[2] += a * bflo(p.y); acc[3] += a * bfhi(p.y);
            acc[4] += a * bflo(p.z); acc[5] += a * bfhi(p.z);
            acc[6] += a * bflo(p.w); acc[7] += a * bfhi(p.w);
        }
        __syncthreads();
    }
    const int c8 = lane * 8;
    float bv[8];
    *(float4*)(bv)     = *(const float4*)(b1 + c8);
    *(float4*)(bv + 4) = *(const float4*)(b1 + c8 + 4);
    union { bf16 b[8]; uint4 u; } hh, ll;
#pragma unroll
    for (int j = 0; j < 8; j++) {
        float t = acc[j] + bv[j];
        float o = t > 0.f ? t : expm1f(t);
        bf16 hb = (bf16)o;
        hh.b[j] = hb;
        ll.b[j] = (bf16)(o - (float)hb);
    }
    *(uint4*)(h1eh + (size_t)n * F1 + c8) = hh.u;
    *(uint4*)(h1el + (size_t)n * F1 + c8) = ll.u;
}

// -------- layer 2 softmax + aggregate: ONE WAVE per node --------
__global__ __launch_bounds__(64) void agg2(const bf16* __restrict__ h2b,
                                           const float* __restrict__ as2,
                                           const float* __restrict__ ad2,
                                           const int* __restrict__ offs,
                                           const int* __restrict__ csr_src,
                                           const int* __restrict__ csr_eid,
                                           const float* __restrict__ b2,
                                           float* __restrict__ alpha2,
                                           float* __restrict__ out) {
    const int n = blockIdx.x;
    const int lane = threadIdx.x;
    const int beg = offs[n];
    const int deg = offs[n + 1] - beg;

    __shared__ int   s_src[64];
    __shared__ float s_al[64];

    const float adn = ad2[n];

    float v0 = 0.f;
    int s0 = 0, e0 = 0;
    float mx = -3e38f;
    for (int idx = lane; idx < deg; idx += 64) {
        int s = csr_src[beg + idx];
        float v = as2[s] + adn;
        v = v > 0.f ? v : 0.2f * v;
        mx = fmaxf(mx, v);
        if (idx == lane) { s0 = s; e0 = csr_eid[beg + idx]; v0 = v; }
    }
#pragma unroll
    for (int o = 1; o < 64; o <<= 1) mx = fmaxf(mx, __shfl_xor(mx, o));

    float ex0 = 0.f, ls = 0.f;
    if (lane < deg) { ex0 = __expf(v0 - mx); ls = ex0; }
    for (int idx = lane + 64; idx < deg; idx += 64) {
        int s = csr_src[beg + idx];
        float v = as2[s] + adn;
        v = v > 0.f ? v : 0.2f * v;
        ls += __expf(v - mx);
    }
#pragma unroll
    for (int o = 1; o < 64; o <<= 1) ls += __shfl_xor(ls, o);
    float rden = 1.f / ls;

    float acc[4] = {};
    for (int base = 0; base < deg; base += 64) {
        int idx = base + lane;
        if (idx < deg) {
            int s, e;
            float a;
            if (base == 0) { s = s0; e = e0; a = ex0 * rden; }
            else {
                s = csr_src[beg + idx];
                e = csr_eid[beg + idx];
                float v = as2[s] + adn;
                v = v > 0.f ? v : 0.2f * v;
                a = __expf(v - mx) * rden;
            }
            s_src[lane] = s;
            s_al[lane] = a;
            alpha2[e] = a;
        }
        __syncthreads();
        int cnt = min(64, deg - base);
        for (int i = 0; i < cnt; i++) {
            int s = s_src[i];
            float a = s_al[i];
            uint2 p = *(const uint2*)(h2b + (size_t)s * F2 + lane * 4);
            acc[0] += a * bflo(p.x); acc[1] += a * bfhi(p.x);
            acc[2] += a * bflo(p.y); acc[3] += a * bfhi(p.y);
        }
        __syncthreads();
    }
    const int c4 = lane * 4;
    float4 bv = *(const float4*)(b2 + c4);
    *(float4*)(out + (size_t)n * F2 + c4) =
        make_float4(acc[0] + bv.x, acc[1] + bv.y, acc[2] + bv.z, acc[3] + bv.w);
}

// ---------------- launch ----------------
extern "C" void kernel_launch(void* const* d_in, const int* in_sizes, int n_in,
                              void* d_out, int out_size, void* d_ws, size_t ws_size,
                              hipStream_t stream) {
    const float* x      = (const float*)d_in[0];
    const int*   ei     = (const int*)d_in[1];
    const float* W1     = (const float*)d_in[2];
    const float* a_src1 = (const float*)d_in[3];
    const float* a_dst1 = (const float*)d_in[4];
    const float* b1     = (const float*)d_in[5];
    const float* W2     = (const float*)d_in[6];
    const float* a_src2 = (const float*)d_in[7];
    const float* a_dst2 = (const float*)d_in[8];
    const float* b2     = (const float*)d_in[9];

    char* ws = (char*)d_ws;
    size_t off = 0;
    auto alloc = [&](size_t bytes) -> char* {
        char* p = ws + off;
        off += (bytes + 255) & ~(size_t)255;
        return p;
    };
    bf16*  h1b  = (bf16*) alloc((size_t)NNODES * F1 * 2);   // 20.5 MB
    bf16*  h2b  = (bf16*) alloc((size_t)NNODES * F2 * 2);   // 10.2 MB
    bf16*  h1eh = (bf16*) alloc((size_t)NNODES * F1 * 2);   // 20.5 MB
    bf16*  h1el = (bf16*) alloc((size_t)NNODES * F1 * 2);   // 20.5 MB
    bf16*  Xh   = (bf16*) alloc((size_t)NNODES * F1 * 2);   // 20.5 MB
    bf16*  Xl   = (bf16*) alloc((size_t)NNODES * F1 * 2);   // 20.5 MB
    float* as1  = (float*)alloc((size_t)NNODES * 4 * 4);
    float* ad1  = (float*)alloc((size_t)NNODES * 4 * 4);
    float* as2  = (float*)alloc((size_t)NNODES * 4);
    float* ad2  = (float*)alloc((size_t)NNODES * 4);
    bf16*  W1h  = (bf16*) alloc((size_t)512 * 512 * 2);
    bf16*  W1l  = (bf16*) alloc((size_t)512 * 512 * 2);
    bf16*  W2h  = (bf16*) alloc((size_t)512 * 256 * 2);
    bf16*  W2l  = (bf16*) alloc((size_t)512 * 256 * 2);
    int*   deg  = (int*)  alloc((size_t)NNODES * 4);
    int*   offs = (int*)  alloc((size_t)(NNODES + 1) * 4);
    int*   cur  = (int*)  alloc((size_t)NNODES * 4);
    int*   csrS = (int*)  alloc((size_t)ETOT * 4);
    int*   csrE = (int*)  alloc((size_t)ETOT * 4);

    float* out2   = (float*)d_out;                      // [20000,256]
    float* alpha1 = out2 + (size_t)NNODES * F2;         // [340000,4]
    float* alpha2 = alpha1 + (size_t)ETOT * HEADS;      // [340000]

    hipMemsetAsync(deg, 0, (size_t)NNODES * 4, stream);
    hipMemsetAsync(as1, 0, (size_t)NNODES * 4 * 4, stream);
    hipMemsetAsync(ad1, 0, (size_t)NNODES * 4 * 4, stream);
    hipMemsetAsync(as2, 0, (size_t)NNODES * 4, stream);
    hipMemsetAsync(ad2, 0, (size_t)NNODES * 4, stream);
    deg_count<<<(ETOT + 255) / 256, 256, 0, stream>>>(ei, deg);
    scan_deg<<<1, 1024, 0, stream>>>(deg, offs, cur);
    fill_csr<<<(ETOT + 255) / 256, 256, 0, stream>>>(ei, cur, csrS, csrE);

    swizzle_w<<<(512 * 512 / 8 + 255) / 256, 256, 0, stream>>>(W1, W1h, W1l, 512, 512);
    swizzle_w<<<(512 * 256 / 8 + 255) / 256, 256, 0, stream>>>(W2, W2h, W2l, 512, 256);
    split_f32<<<(NNODES * F1 / 8 + 255) / 256, 256, 0, stream>>>(
        x, Xh, Xl, NNODES * F1 / 8);

    gemm_fused<512, 512><<<dim3(157, 8), 256, 0, stream>>>(
        Xh, Xl, W1h, W1l, h1b, a_src1, a_dst1, as1, ad1, NNODES);
    agg1<<<NNODES, 64, 0, stream>>>(h1b, as1, ad1, offs, csrS, csrE, b1, alpha1,
                                    h1eh, h1el);

    gemm_fused<512, 256><<<dim3(157, 4), 256, 0, stream>>>(
        h1eh, h1el, W2h, W2l, h2b, a_src2, a_dst2, as2, ad2, NNODES);
    agg2<<<NNODES, 64, 0, stream>>>(h2b, as2, ad2, offs, csrS, csrE, b2, alpha2, out2);
}

// Round 2
// 346.041 us; speedup vs baseline: 1.0712x; 1.0712x over previous
//
#include <hip/hip_runtime.h>
#include <hip/hip_bf16.h>
#include <cstdint>

// SimpleGAT on MI355X. Round 8:
//   R7 @370us REGRESSION vs R6 @325us. gemm1 90us: FETCH doubled 85->184MB
//   (64-col blocks -> A re-read x8, same-row blocks 157 apart in dispatch ->
//   no L2/L3 reuse). VALU-hoist DID work (VALUBusy 20->8).
// Changes:
//   1. Restore 128-col blocks (A re-read x4/x2), keep 2 row-frags/wave:
//      48 MFMA : 16 ds_read per kt (3:1). LDS 2x16KB.
//   2. XCD-aware swizzle: same-row col-blocks get ids {i,i+8,i+16,i+24} ->
//      same XCD consecutively -> A slab (256KB) L2-resident across them.
//   3. gemm1 128 cols == one head -> direct as1/ad1 stores again (no atomics).
//
// MFMA 16x16x32 bf16 layouts (verified R3-R5):
//   A: lane holds A[m=lane&15][k=(lane>>4)*8 + j], j=0..7
//   B: lane holds B[k=(lane>>4)*8 + j][n=lane&15]   (pre-swizzled contiguous)
//   C/D: col = lane&15, row = (lane>>4)*4 + reg

#define NNODES 20000
#define NEDGES 320000
#define ETOT   340000   // NEDGES + NNODES self loops
#define F1     512      // HEADS*HID
#define F2     256      // OUT_CH
#define HEADS  4

typedef __bf16 bf16;
typedef __attribute__((ext_vector_type(8))) __bf16 bf16x8;
typedef __attribute__((ext_vector_type(4))) float f32x4;

__device__ __forceinline__ float bflo(unsigned p) { return __uint_as_float(p << 16); }
__device__ __forceinline__ float bfhi(unsigned p) { return __uint_as_float(p & 0xffff0000u); }

__device__ __forceinline__ void gload_lds16(const void* g, void* l) {
    __builtin_amdgcn_global_load_lds(
        (const __attribute__((address_space(1))) void*)g,
        (__attribute__((address_space(3))) void*)l, 16, 0, 0);
}

// ---------------- CSR build ----------------
__global__ void deg_count(const int* __restrict__ ei, int* __restrict__ deg) {
    int e = blockIdx.x * blockDim.x + threadIdx.x;
    if (e >= ETOT) return;
    int dst = (e < NEDGES) ? ei[NEDGES + e] : (e - NEDGES);
    atomicAdd(&deg[dst], 1);
}

// 1024 threads, 20 elems each (20480 >= 20000); one block-scan.
__global__ void scan_deg(const int* __restrict__ deg, int* __restrict__ offs,
                         int* __restrict__ cur) {
    __shared__ int sums[1024];
    const int t = threadIdx.x;
    const int PER = 20;
    int base = t * PER;
    int local[PER];
    int run = 0;
#pragma unroll
    for (int j = 0; j < PER; j++) {
        int i = base + j;
        int v = (i < NNODES) ? deg[i] : 0;
        local[j] = run;
        run += v;
    }
    sums[t] = run;
    __syncthreads();
    for (int o = 1; o < 1024; o <<= 1) {
        int v = (t >= o) ? sums[t - o] : 0;
        __syncthreads();
        sums[t] += v;
        __syncthreads();
    }
    int texcl = (t == 0) ? 0 : sums[t - 1];
#pragma unroll
    for (int j = 0; j < PER; j++) {
        int i = base + j;
        if (i < NNODES) {
            int e = texcl + local[j];
            cur[i] = e;
            offs[i] = e;
        }
    }
    if (t == 1023) offs[NNODES] = sums[1023];
}

__global__ void fill_csr(const int* __restrict__ ei, int* __restrict__ cur,
                         int* __restrict__ csr_src, int* __restrict__ csr_eid) {
    int e = blockIdx.x * blockDim.x + threadIdx.x;
    if (e >= ETOT) return;
    int src, dst;
    if (e < NEDGES) { src = ei[e]; dst = ei[NEDGES + e]; }
    else            { src = dst = e - NEDGES; }
    int p = atomicAdd(&cur[dst], 1);
    csr_src[p] = src;
    csr_eid[p] = e;
}

// ---------------- W swizzle (fp32 -> hi/lo bf16 B-fragment order) ----------------
__global__ void swizzle_w(const float* __restrict__ W, bf16* __restrict__ Wh,
                          bf16* __restrict__ Wl, int K, int N) {
    int idx = blockIdx.x * blockDim.x + threadIdx.x;  // one thread per 8 elements
    int total = (K * N) >> 3;
    if (idx >= total) return;
    int lane = idx & 63;
    int tile = idx >> 6;            // kt*(N/16) + nt
    int NT = N >> 4;
    int kt = tile / NT, nt = tile - kt * NT;
    int krow = kt * 32 + (lane >> 4) * 8;
    int col  = nt * 16 + (lane & 15);
    union { bf16 b[8]; uint4 u; } hi, lo;
#pragma unroll
    for (int j = 0; j < 8; j++) {
        float w = W[(size_t)(krow + j) * N + col];
        bf16 h = (bf16)w;
        hi.b[j] = h;
        lo.b[j] = (bf16)(w - (float)h);
    }
    *(uint4*)(Wh + (size_t)idx * 8) = hi.u;
    *(uint4*)(Wl + (size_t)idx * 8) = lo.u;
}

// ---------------- fp32 -> split hi/lo bf16, row-major ----------------
__global__ void split_f32(const float* __restrict__ X, bf16* __restrict__ Xh,
                          bf16* __restrict__ Xl, int total8) {
    int i = blockIdx.x * blockDim.x + threadIdx.x;
    if (i >= total8) return;
    float v[8];
    *(float4*)(v)     = *(const float4*)(X + (size_t)i * 8);
    *(float4*)(v + 4) = *(const float4*)(X + (size_t)i * 8 + 4);
    union { bf16 b[8]; uint4 u; } h, l;
#pragma unroll
    for (int j = 0; j < 8; j++) {
        bf16 hh = (bf16)v[j];
        h.b[j] = hh;
        l.b[j] = (bf16)(v[j] - (float)hh);
    }
    *(uint4*)(Xh + (size_t)i * 8) = h.u;
    *(uint4*)(Xl + (size_t)i * 8) = l.u;
}

// ------- split-bf16 MFMA GEMM, LDS-staged B, fused attn-coef epilogue -------
// block = 4 waves; wave owns 32 rows (2 frags) x 128 cols (8 tiles).
// LDS per kt: [hi 8KB | lo 8KB]; double-buffered. A pre-split bf16, reg-prefetched.
// 1-D grid, XCD-swizzled: same-row col-blocks -> same XCD back-to-back.
template <int K, int N, int NYB>
__global__ __launch_bounds__(256) void gemm_fused(const bf16* __restrict__ Ah,
                                                  const bf16* __restrict__ Al,
                                                  const bf16* __restrict__ Bh,
                                                  const bf16* __restrict__ Bl,
                                                  bf16* __restrict__ Cb,
                                                  const float* __restrict__ asrc,
                                                  const float* __restrict__ adst,
                                                  float* __restrict__ as_out,
                                                  float* __restrict__ ad_out, int M) {
    __shared__ __align__(16) char smem[2][16384];
    const int lane = threadIdx.x & 63;
    const int wave = threadIdx.x >> 6;
    constexpr int NT = N / 16;
    constexpr int NKT = K / 32;
    constexpr int CH = 8 * NYB;     // ids per swizzle chunk (8 XCDs x NYB)

    // XCD swizzle: ids {i, i+8, .., i+8*(NYB-1)} (same XCD) -> same row-slab.
    const int nb = gridDim.x;
    const int full = (nb / CH) * CH;
    int bx, by;
    {
        int id = blockIdx.x;
        if (id < full) {
            int chunk = id / CH, pos = id % CH;
            bx = chunk * 8 + (pos & 7);
            by = pos >> 3;
        } else {
            int r = id - full;
            int x0 = full / NYB;           // = 8 * nchunks
            int remx = nb / NYB - x0;
            bx = x0 + r % remx;
            by = r / remx;
        }
    }
    const int row_base = bx * 128 + wave * 32;
    const int colt0 = by * 8;       // 8 col-tiles of 16 = 128 cols

    const char* hbase = (const char*)Bh + (size_t)colt0 * 1024;
    const char* lbase = (const char*)Bl + (size_t)colt0 * 1024;
    // stage 16KB (8KB hi + 8KB lo) for K-slice kt; each wave moves 4KB.
    auto stage = [&](int kt, int buf) {
        size_t kb = (size_t)kt * NT * 1024;
#pragma unroll
        for (int q = 0; q < 4; q++) {
            int off = wave * 4096 + q * 1024;
            const char* src = (off < 8192) ? (hbase + kb + off)
                                           : (lbase + kb + (off - 8192));
            gload_lds16(src + lane * 16, &smem[buf][off]);
        }
    };

    int arow0 = row_base + (lane & 15);
    int arow1 = arow0 + 16;
    if (arow0 >= M) arow0 = M - 1;      // clamp; stores are guarded
    if (arow1 >= M) arow1 = M - 1;
    const int ko = (lane >> 4) * 8;
    const bf16* pah0 = Ah + (size_t)arow0 * K + ko;
    const bf16* pal0 = Al + (size_t)arow0 * K + ko;
    const bf16* pah1 = Ah + (size_t)arow1 * K + ko;
    const bf16* pal1 = Al + (size_t)arow1 * K + ko;

    f32x4 acc0[8] = {}, acc1[8] = {};
    bf16x8 ah0 = *(const bf16x8*)pah0;
    bf16x8 al0 = *(const bf16x8*)pal0;
    bf16x8 ah1 = *(const bf16x8*)pah1;
    bf16x8 al1 = *(const bf16x8*)pal1;

    auto body = [&](const char* bb) {
#pragma unroll
        for (int c = 0; c < 8; c++) {
            bf16x8 bh = *(const bf16x8*)(bb + c * 1024 + lane * 16);
            bf16x8 bl = *(const bf16x8*)(bb + 8192 + c * 1024 + lane * 16);
            acc0[c] = __builtin_amdgcn_mfma_f32_16x16x32_bf16(ah0, bh, acc0[c], 0, 0, 0);
            acc1[c] = __builtin_amdgcn_mfma_f32_16x16x32_bf16(ah1, bh, acc1[c], 0, 0, 0);
            acc0[c] = __builtin_amdgcn_mfma_f32_16x16x32_bf16(ah0, bl, acc0[c], 0, 0, 0);
            acc1[c] = __builtin_amdgcn_mfma_f32_16x16x32_bf16(ah1, bl, acc1[c], 0, 0, 0);
            acc0[c] = __builtin_amdgcn_mfma_f32_16x16x32_bf16(al0, bh, acc0[c], 0, 0, 0);
            acc1[c] = __builtin_amdgcn_mfma_f32_16x16x32_bf16(al1, bh, acc1[c], 0, 0, 0);
        }
    };

    stage(0, 0);
    __syncthreads();
    for (int kt = 0; kt < NKT - 1; ++kt) {
        stage(kt + 1, (kt + 1) & 1);
        bf16x8 nah0 = *(const bf16x8*)(pah0 + (kt + 1) * 32);
        bf16x8 nal0 = *(const bf16x8*)(pal0 + (kt + 1) * 32);
        bf16x8 nah1 = *(const bf16x8*)(pah1 + (kt + 1) * 32);
        bf16x8 nal1 = *(const bf16x8*)(pal1 + (kt + 1) * 32);
        body(smem[kt & 1]);
        __syncthreads();
        ah0 = nah0; al0 = nal0; ah1 = nah1; al1 = nal1;
    }
    body(smem[(NKT - 1) & 1]);

    const int crow0 = row_base + (lane >> 4) * 4;  // frag0 rows; frag1 = +16
    const int col15 = lane & 15;
#pragma unroll
    for (int c = 0; c < 8; c++)
#pragma unroll
        for (int r = 0; r < 4; r++) {
            int r0 = crow0 + r, r1 = r0 + 16;
            int cc = (colt0 + c) * 16 + col15;
            if (r0 < M) Cb[(size_t)r0 * N + cc] = (bf16)acc0[c][r];
            if (r1 < M) Cb[(size_t)r1 * N + cc] = (bf16)acc1[c][r];
        }

    // fused attention coefficient dots (block's 128 cols)
    float ss0[4] = {}, sd0[4] = {}, ss1[4] = {}, sd1[4] = {};
#pragma unroll
    for (int c = 0; c < 8; c++) {
        int cw = by * 128 + c * 16 + col15;          // global column
        float was = asrc[cw];                         // asrc laid out [H*128]/[256]
        float wad = adst[cw];
#pragma unroll
        for (int r = 0; r < 4; r++) {
            ss0[r] += acc0[c][r] * was; sd0[r] += acc0[c][r] * wad;
            ss1[r] += acc1[c][r] * was; sd1[r] += acc1[c][r] * wad;
        }
    }
#pragma unroll
    for (int o = 1; o < 16; o <<= 1)
#pragma unroll
        for (int r = 0; r < 4; r++) {
            ss0[r] += __shfl_xor(ss0[r], o); sd0[r] += __shfl_xor(sd0[r], o);
            ss1[r] += __shfl_xor(ss1[r], o); sd1[r] += __shfl_xor(sd1[r], o);
        }
    if (col15 == 0) {
        if constexpr (N == 512) {        // block cols == one head: direct store
#pragma unroll
            for (int r = 0; r < 4; r++) {
                int r0 = crow0 + r, r1 = r0 + 16;
                if (r0 < M) { as_out[r0 * 4 + by] = ss0[r]; ad_out[r0 * 4 + by] = sd0[r]; }
                if (r1 < M) { as_out[r1 * 4 + by] = ss1[r]; ad_out[r1 * 4 + by] = sd1[r]; }
            }
        } else {                         // half of the single head: atomics
#pragma unroll
            for (int r = 0; r < 4; r++) {
                int r0 = crow0 + r, r1 = r0 + 16;
                if (r0 < M) { atomicAdd(&as_out[r0], ss0[r]); atomicAdd(&ad_out[r0], sd0[r]); }
                if (r1 < M) { atomicAdd(&as_out[r1], ss1[r]); atomicAdd(&ad_out[r1], sd1[r]); }
            }
        }
    }
}

// -------- layer 1 softmax + aggregate: ONE WAVE per node --------
__global__ __launch_bounds__(64) void agg1(const bf16* __restrict__ h1b,
                                           const float* __restrict__ as1,
                                           const float* __restrict__ ad1,
                                           const int* __restrict__ offs,
                                           const int* __restrict__ csr_src,
                                           const int* __restrict__ csr_eid,
                                           const float* __restrict__ b1,
                                           float* __restrict__ alpha1,
                                           bf16* __restrict__ h1eh,
                                           bf16* __restrict__ h1el) {
    const int n = blockIdx.x;
    const int lane = threadIdx.x;
    const int beg = offs[n];
    const int deg = offs[n + 1] - beg;

    __shared__ int   s_src[64];
    __shared__ float s_al[64][4];

    float4 ad4 = *(const float4*)(ad1 + n * 4);
    const float adn[4] = {ad4.x, ad4.y, ad4.z, ad4.w};

    float v0[4];
    int s0 = 0, e0 = 0;
    float mx[4] = {-3e38f, -3e38f, -3e38f, -3e38f};
    for (int idx = lane; idx < deg; idx += 64) {
        int s = csr_src[beg + idx];
        float4 a4 = *(const float4*)(as1 + s * 4);
        float v[4] = {a4.x + adn[0], a4.y + adn[1], a4.z + adn[2], a4.w + adn[3]};
#pragma unroll
        for (int h = 0; h < 4; h++) {
            v[h] = v[h] > 0.f ? v[h] : 0.2f * v[h];
            mx[h] = fmaxf(mx[h], v[h]);
        }
        if (idx == lane) {
            s0 = s; e0 = csr_eid[beg + idx];
#pragma unroll
            for (int h = 0; h < 4; h++) v0[h] = v[h];
        }
    }
#pragma unroll
    for (int o = 1; o < 64; o <<= 1)
#pragma unroll
        for (int h = 0; h < 4; h++) mx[h] = fmaxf(mx[h], __shfl_xor(mx[h], o));

    float ex0[4] = {0.f, 0.f, 0.f, 0.f};
    float ls[4] = {0.f, 0.f, 0.f, 0.f};
    if (lane < deg) {
#pragma unroll
        for (int h = 0; h < 4; h++) { ex0[h] = __expf(v0[h] - mx[h]); ls[h] = ex0[h]; }
    }
    for (int idx = lane + 64; idx < deg; idx += 64) {
        int s = csr_src[beg + idx];
        float4 a4 = *(const float4*)(as1 + s * 4);
        float v[4] = {a4.x + adn[0], a4.y + adn[1], a4.z + adn[2], a4.w + adn[3]};
#pragma unroll
        for (int h = 0; h < 4; h++) {
            v[h] = v[h] > 0.f ? v[h] : 0.2f * v[h];
            ls[h] += __expf(v[h] - mx[h]);
        }
    }
#pragma unroll
    for (int o = 1; o < 64; o <<= 1)
#pragma unroll
        for (int h = 0; h < 4; h++) ls[h] += __shfl_xor(ls[h], o);
    float rden[4];
#pragma unroll
    for (int h = 0; h < 4; h++) rden[h] = 1.f / ls[h];

    float acc[8] = {};
    const int myh = lane >> 4;
    for (int base = 0; base < deg; base += 64) {
        int idx = base + lane;
        if (idx < deg) {
            int s, e;
            float al[4];
            if (base == 0) {
                s = s0; e = e0;
#pragma unroll
                for (int h = 0; h < 4; h++) al[h] = ex0[h] * rden[h];
            } else {
                s = csr_src[beg + idx];
                e = csr_eid[beg + idx];
                float4 a4 = *(const float4*)(as1 + s * 4);
                float v[4] = {a4.x + adn[0], a4.y + adn[1], a4.z + adn[2], a4.w + adn[3]};
#pragma unroll
                for (int h = 0; h < 4; h++) {
                    v[h] = v[h] > 0.f ? v[h] : 0.2f * v[h];
                    al[h] = __expf(v[h] - mx[h]) * rden[h];
                }
            }
            s_src[lane] = s;
#pragma unroll
            for (int h = 0; h < 4; h++) s_al[lane][h] = al[h];
            *(float4*)(alpha1 + (size_t)e * 4) = make_float4(al[0], al[1], al[2], al[3]);
        }
        __syncthreads();
        int cnt = min(64, deg - base);
        for (int i = 0; i < cnt; i++) {
            int s = s_src[i];
            float a = s_al[i][myh];
            uint4 p = *(const uint4*)(h1b + (size_t)s * F1 + lane * 8);
            acc[0] += a * bflo(p.x); acc[1] += a * bfhi(p.x);
            acc[2] += a * bflo(p.y); acc[3] += a * bfhi(p.y);
            acc[4] += a * bflo(p.z); acc[5] += a * bfhi(p.z);
            acc[6] += a * bflo(p.w); acc[7] += a * bfhi(p.w);
        }
        __syncthreads();
    }
    const int c8 = lane * 8;
    float bv[8];
    *(float4*)(bv)     = *(const float4*)(b1 + c8);
    *(float4*)(bv + 4) = *(const float4*)(b1 + c8 + 4);
    union { bf16 b[8]; uint4 u; } hh, ll;
#pragma unroll
    for (int j = 0; j < 8; j++) {
        float t = acc[j] + bv[j];
        float o = t > 0.f ? t : expm1f(t);
        bf16 hb = (bf16)o;
        hh.b[j] = hb;
        ll.b[j] = (bf16)(o - (float)hb);
    }
    *(uint4*)(h1eh + (size_t)n * F1 + c8) = hh.u;
    *(uint4*)(h1el + (size_t)n * F1 + c8) = ll.u;
}

// -------- layer 2 softmax + aggregate: ONE WAVE per node --------
__global__ __launch_bounds__(64) void agg2(const bf16* __restrict__ h2b,
                                           const float* __restrict__ as2,
                                           const float* __restrict__ ad2,
                                           const int* __restrict__ offs,
                                           const int* __restrict__ csr_src,
                                           const int* __restrict__ csr_eid,
                                           const float* __restrict__ b2,
                                           float* __restrict__ alpha2,
                                           float* __restrict__ out) {
    const int n = blockIdx.x;
    const int lane = threadIdx.x;
    const int beg = offs[n];
    const int deg = offs[n + 1] - beg;

    __shared__ int   s_src[64];
    __shared__ float s_al[64];

    const float adn = ad2[n];

    float v0 = 0.f;
    int s0 = 0, e0 = 0;
    float mx = -3e38f;
    for (int idx = lane; idx < deg; idx += 64) {
        int s = csr_src[beg + idx];
        float v = as2[s] + adn;
        v = v > 0.f ? v : 0.2f * v;
        mx = fmaxf(mx, v);
        if (idx == lane) { s0 = s; e0 = csr_eid[beg + idx]; v0 = v; }
    }
#pragma unroll
    for (int o = 1; o < 64; o <<= 1) mx = fmaxf(mx, __shfl_xor(mx, o));

    float ex0 = 0.f, ls = 0.f;
    if (lane < deg) { ex0 = __expf(v0 - mx); ls = ex0; }
    for (int idx = lane + 64; idx < deg; idx += 64) {
        int s = csr_src[beg + idx];
        float v = as2[s] + adn;
        v = v > 0.f ? v : 0.2f * v;
        ls += __expf(v - mx);
    }
#pragma unroll
    for (int o = 1; o < 64; o <<= 1) ls += __shfl_xor(ls, o);
    float rden = 1.f / ls;

    float acc[4] = {};
    for (int base = 0; base < deg; base += 64) {
        int idx = base + lane;
        if (idx < deg) {
            int s, e;
            float a;
            if (base == 0) { s = s0; e = e0; a = ex0 * rden; }
            else {
                s = csr_src[beg + idx];
                e = csr_eid[beg + idx];
                float v = as2[s] + adn;
                v = v > 0.f ? v : 0.2f * v;
                a = __expf(v - mx) * rden;
            }
            s_src[lane] = s;
            s_al[lane] = a;
            alpha2[e] = a;
        }
        __syncthreads();
        int cnt = min(64, deg - base);
        for (int i = 0; i < cnt; i++) {
            int s = s_src[i];
            float a = s_al[i];
            uint2 p = *(const uint2*)(h2b + (size_t)s * F2 + lane * 4);
            acc[0] += a * bflo(p.x); acc[1] += a * bfhi(p.x);
            acc[2] += a * bflo(p.y); acc[3] += a * bfhi(p.y);
        }
        __syncthreads();
    }
    const int c4 = lane * 4;
    float4 bv = *(const float4*)(b2 + c4);
    *(float4*)(out + (size_t)n * F2 + c4) =
        make_float4(acc[0] + bv.x, acc[1] + bv.y, acc[2] + bv.z, acc[3] + bv.w);
}

// ---------------- launch ----------------
extern "C" void kernel_launch(void* const* d_in, const int* in_sizes, int n_in,
                              void* d_out, int out_size, void* d_ws, size_t ws_size,
                              hipStream_t stream) {
    const float* x      = (const float*)d_in[0];
    const int*   ei     = (const int*)d_in[1];
    const float* W1     = (const float*)d_in[2];
    const float* a_src1 = (const float*)d_in[3];
    const float* a_dst1 = (const float*)d_in[4];
    const float* b1     = (const float*)d_in[5];
    const float* W2     = (const float*)d_in[6];
    const float* a_src2 = (const float*)d_in[7];
    const float* a_dst2 = (const float*)d_in[8];
    const float* b2     = (const float*)d_in[9];

    char* ws = (char*)d_ws;
    size_t off = 0;
    auto alloc = [&](size_t bytes) -> char* {
        char* p = ws + off;
        off += (bytes + 255) & ~(size_t)255;
        return p;
    };
    bf16*  h1b  = (bf16*) alloc((size_t)NNODES * F1 * 2);   // 20.5 MB
    bf16*  h2b  = (bf16*) alloc((size_t)NNODES * F2 * 2);   // 10.2 MB
    bf16*  h1eh = (bf16*) alloc((size_t)NNODES * F1 * 2);   // 20.5 MB
    bf16*  h1el = (bf16*) alloc((size_t)NNODES * F1 * 2);   // 20.5 MB
    bf16*  Xh   = (bf16*) alloc((size_t)NNODES * F1 * 2);   // 20.5 MB
    bf16*  Xl   = (bf16*) alloc((size_t)NNODES * F1 * 2);   // 20.5 MB
    float* as1  = (float*)alloc((size_t)NNODES * 4 * 4);
    float* ad1  = (float*)alloc((size_t)NNODES * 4 * 4);
    float* as2  = (float*)alloc((size_t)NNODES * 4);
    float* ad2  = (float*)alloc((size_t)NNODES * 4);
    bf16*  W1h  = (bf16*) alloc((size_t)512 * 512 * 2);
    bf16*  W1l  = (bf16*) alloc((size_t)512 * 512 * 2);
    bf16*  W2h  = (bf16*) alloc((size_t)512 * 256 * 2);
    bf16*  W2l  = (bf16*) alloc((size_t)512 * 256 * 2);
    int*   deg  = (int*)  alloc((size_t)NNODES * 4);
    int*   offs = (int*)  alloc((size_t)(NNODES + 1) * 4);
    int*   cur  = (int*)  alloc((size_t)NNODES * 4);
    int*   csrS = (int*)  alloc((size_t)ETOT * 4);
    int*   csrE = (int*)  alloc((size_t)ETOT * 4);

    float* out2   = (float*)d_out;                      // [20000,256]
    float* alpha1 = out2 + (size_t)NNODES * F2;         // [340000,4]
    float* alpha2 = alpha1 + (size_t)ETOT * HEADS;      // [340000]

    hipMemsetAsync(deg, 0, (size_t)NNODES * 4, stream);
    hipMemsetAsync(as2, 0, (size_t)NNODES * 4, stream);
    hipMemsetAsync(ad2, 0, (size_t)NNODES * 4, stream);
    deg_count<<<(ETOT + 255) / 256, 256, 0, stream>>>(ei, deg);
    scan_deg<<<1, 1024, 0, stream>>>(deg, offs, cur);
    fill_csr<<<(ETOT + 255) / 256, 256, 0, stream>>>(ei, cur, csrS, csrE);

    swizzle_w<<<(512 * 512 / 8 + 255) / 256, 256, 0, stream>>>(W1, W1h, W1l, 512, 512);
    swizzle_w<<<(512 * 256 / 8 + 255) / 256, 256, 0, stream>>>(W2, W2h, W2l, 512, 256);
    split_f32<<<(NNODES * F1 / 8 + 255) / 256, 256, 0, stream>>>(
        x, Xh, Xl, NNODES * F1 / 8);

    gemm_fused<512, 512, 4><<<157 * 4, 256, 0, stream>>>(
        Xh, Xl, W1h, W1l, h1b, a_src1, a_dst1, as1, ad1, NNODES);
    agg1<<<NNODES, 64, 0, stream>>>(h1b, as1, ad1, offs, csrS, csrE, b1, alpha1,
                                    h1eh, h1el);

    gemm_fused<512, 256, 2><<<157 * 2, 256, 0, stream>>>(
        h1eh, h1el, W2h, W2l, h2b, a_src2, a_dst2, as2, ad2, NNODES);
    agg2<<<NNODES, 64, 0, stream>>>(h2b, as2, ad2, offs, csrS, csrE, b2, alpha2, out2);
}

// Round 3
// 339.197 us; speedup vs baseline: 1.0928x; 1.0202x over previous
//
#include <hip/hip_runtime.h>
#include <hip/hip_bf16.h>
#include <cstdint>

// SimpleGAT on MI355X. Round 9:
//   R8 @346us. gemm1 62us: swizzle fixed traffic (FETCH 184->28.8MB, HBM 12%)
//   but Occupancy fell to 13% (628 4-wave blocks = ~1 block/CU resident) ->
//   1 wave/SIMD, no TLP, per-kt ds_read->MFMA->barrier chain fully exposed.
//   MFMA floor ~15us; 62us is latency, not any pipe.
// Changes:
//   1. Blocks: 4 waves/128 rows -> 2 waves/64 rows. Per-wave shape unchanged
//      (2 row-frags x 8 col-tiles, 48 MFMA : 16 ds_read per kt). Grid doubles
//      to 1252/626 -> ~4.9 blocks/CU launched, 5 fit by LDS (32KB) -> ~10
//      waves/CU (~2.5/SIMD) for latency hiding.
//   2. Same XCD swizzle (ids {i,i+8,i+16,i+24} share a 64-row A-slab on one
//      XCD) -> FETCH stays ~29MB.
//
// MFMA 16x16x32 bf16 layouts (verified R3-R5):
//   A: lane holds A[m=lane&15][k=(lane>>4)*8 + j], j=0..7
//   B: lane holds B[k=(lane>>4)*8 + j][n=lane&15]   (pre-swizzled contiguous)
//   C/D: col = lane&15, row = (lane>>4)*4 + reg

#define NNODES 20000
#define NEDGES 320000
#define ETOT   340000   // NEDGES + NNODES self loops
#define F1     512      // HEADS*HID
#define F2     256      // OUT_CH
#define HEADS  4

typedef __bf16 bf16;
typedef __attribute__((ext_vector_type(8))) __bf16 bf16x8;
typedef __attribute__((ext_vector_type(4))) float f32x4;

__device__ __forceinline__ float bflo(unsigned p) { return __uint_as_float(p << 16); }
__device__ __forceinline__ float bfhi(unsigned p) { return __uint_as_float(p & 0xffff0000u); }

__device__ __forceinline__ void gload_lds16(const void* g, void* l) {
    __builtin_amdgcn_global_load_lds(
        (const __attribute__((address_space(1))) void*)g,
        (__attribute__((address_space(3))) void*)l, 16, 0, 0);
}

// ---------------- CSR build ----------------
__global__ void deg_count(const int* __restrict__ ei, int* __restrict__ deg) {
    int e = blockIdx.x * blockDim.x + threadIdx.x;
    if (e >= ETOT) return;
    int dst = (e < NEDGES) ? ei[NEDGES + e] : (e - NEDGES);
    atomicAdd(&deg[dst], 1);
}

// 1024 threads, 20 elems each (20480 >= 20000); one block-scan.
__global__ void scan_deg(const int* __restrict__ deg, int* __restrict__ offs,
                         int* __restrict__ cur) {
    __shared__ int sums[1024];
    const int t = threadIdx.x;
    const int PER = 20;
    int base = t * PER;
    int local[PER];
    int run = 0;
#pragma unroll
    for (int j = 0; j < PER; j++) {
        int i = base + j;
        int v = (i < NNODES) ? deg[i] : 0;
        local[j] = run;
        run += v;
    }
    sums[t] = run;
    __syncthreads();
    for (int o = 1; o < 1024; o <<= 1) {
        int v = (t >= o) ? sums[t - o] : 0;
        __syncthreads();
        sums[t] += v;
        __syncthreads();
    }
    int texcl = (t == 0) ? 0 : sums[t - 1];
#pragma unroll
    for (int j = 0; j < PER; j++) {
        int i = base + j;
        if (i < NNODES) {
            int e = texcl + local[j];
            cur[i] = e;
            offs[i] = e;
        }
    }
    if (t == 1023) offs[NNODES] = sums[1023];
}

__global__ void fill_csr(const int* __restrict__ ei, int* __restrict__ cur,
                         int* __restrict__ csr_src, int* __restrict__ csr_eid) {
    int e = blockIdx.x * blockDim.x + threadIdx.x;
    if (e >= ETOT) return;
    int src, dst;
    if (e < NEDGES) { src = ei[e]; dst = ei[NEDGES + e]; }
    else            { src = dst = e - NEDGES; }
    int p = atomicAdd(&cur[dst], 1);
    csr_src[p] = src;
    csr_eid[p] = e;
}

// ---------------- W swizzle (fp32 -> hi/lo bf16 B-fragment order) ----------------
__global__ void swizzle_w(const float* __restrict__ W, bf16* __restrict__ Wh,
                          bf16* __restrict__ Wl, int K, int N) {
    int idx = blockIdx.x * blockDim.x + threadIdx.x;  // one thread per 8 elements
    int total = (K * N) >> 3;
    if (idx >= total) return;
    int lane = idx & 63;
    int tile = idx >> 6;            // kt*(N/16) + nt
    int NT = N >> 4;
    int kt = tile / NT, nt = tile - kt * NT;
    int krow = kt * 32 + (lane >> 4) * 8;
    int col  = nt * 16 + (lane & 15);
    union { bf16 b[8]; uint4 u; } hi, lo;
#pragma unroll
    for (int j = 0; j < 8; j++) {
        float w = W[(size_t)(krow + j) * N + col];
        bf16 h = (bf16)w;
        hi.b[j] = h;
        lo.b[j] = (bf16)(w - (float)h);
    }
    *(uint4*)(Wh + (size_t)idx * 8) = hi.u;
    *(uint4*)(Wl + (size_t)idx * 8) = lo.u;
}

// ---------------- fp32 -> split hi/lo bf16, row-major ----------------
__global__ void split_f32(const float* __restrict__ X, bf16* __restrict__ Xh,
                          bf16* __restrict__ Xl, int total8) {
    int i = blockIdx.x * blockDim.x + threadIdx.x;
    if (i >= total8) return;
    float v[8];
    *(float4*)(v)     = *(const float4*)(X + (size_t)i * 8);
    *(float4*)(v + 4) = *(const float4*)(X + (size_t)i * 8 + 4);
    union { bf16 b[8]; uint4 u; } h, l;
#pragma unroll
    for (int j = 0; j < 8; j++) {
        bf16 hh = (bf16)v[j];
        h.b[j] = hh;
        l.b[j] = (bf16)(v[j] - (float)hh);
    }
    *(uint4*)(Xh + (size_t)i * 8) = h.u;
    *(uint4*)(Xl + (size_t)i * 8) = l.u;
}

// ------- split-bf16 MFMA GEMM, LDS-staged B, fused attn-coef epilogue -------
// block = 2 waves; wave owns 32 rows (2 frags) x 128 cols (8 tiles).
// LDS per kt: [hi 8KB | lo 8KB]; double-buffered. A pre-split bf16, reg-prefetched.
// 1-D grid, XCD-swizzled: same-row col-blocks -> same XCD back-to-back.
template <int K, int N, int NYB>
__global__ __launch_bounds__(128) void gemm_fused(const bf16* __restrict__ Ah,
                                                  const bf16* __restrict__ Al,
                                                  const bf16* __restrict__ Bh,
                                                  const bf16* __restrict__ Bl,
                                                  bf16* __restrict__ Cb,
                                                  const float* __restrict__ asrc,
                                                  const float* __restrict__ adst,
                                                  float* __restrict__ as_out,
                                                  float* __restrict__ ad_out, int M) {
    __shared__ __align__(16) char smem[2][16384];
    const int lane = threadIdx.x & 63;
    const int wave = threadIdx.x >> 6;
    constexpr int NT = N / 16;
    constexpr int NKT = K / 32;
    constexpr int CH = 8 * NYB;     // ids per swizzle chunk (8 XCDs x NYB)

    // XCD swizzle: ids {i, i+8, .., i+8*(NYB-1)} (same XCD) -> same row-slab.
    const int nb = gridDim.x;
    const int full = (nb / CH) * CH;
    int bx, by;
    {
        int id = blockIdx.x;
        if (id < full) {
            int chunk = id / CH, pos = id % CH;
            bx = chunk * 8 + (pos & 7);
            by = pos >> 3;
        } else {
            int r = id - full;
            int x0 = full / NYB;           // = 8 * nchunks
            int remx = nb / NYB - x0;
            bx = x0 + r % remx;
            by = r / remx;
        }
    }
    const int row_base = bx * 64 + wave * 32;
    const int colt0 = by * 8;       // 8 col-tiles of 16 = 128 cols

    const char* hbase = (const char*)Bh + (size_t)colt0 * 1024;
    const char* lbase = (const char*)Bl + (size_t)colt0 * 1024;
    // stage 16KB (8KB hi + 8KB lo) for K-slice kt; each wave moves 8KB.
    auto stage = [&](int kt, int buf) {
        size_t kb = (size_t)kt * NT * 1024;
#pragma unroll
        for (int q = 0; q < 8; q++) {
            int off = wave * 8192 + q * 1024;
            const char* src = (off < 8192) ? (hbase + kb + off)
                                           : (lbase + kb + (off - 8192));
            gload_lds16(src + lane * 16, &smem[0][0] + buf * 16384 + off);
        }
    };

    int arow0 = row_base + (lane & 15);
    int arow1 = arow0 + 16;
    if (arow0 >= M) arow0 = M - 1;      // clamp; stores are guarded
    if (arow1 >= M) arow1 = M - 1;
    const int ko = (lane >> 4) * 8;
    const bf16* pah0 = Ah + (size_t)arow0 * K + ko;
    const bf16* pal0 = Al + (size_t)arow0 * K + ko;
    const bf16* pah1 = Ah + (size_t)arow1 * K + ko;
    const bf16* pal1 = Al + (size_t)arow1 * K + ko;

    f32x4 acc0[8] = {}, acc1[8] = {};
    bf16x8 ah0 = *(const bf16x8*)pah0;
    bf16x8 al0 = *(const bf16x8*)pal0;
    bf16x8 ah1 = *(const bf16x8*)pah1;
    bf16x8 al1 = *(const bf16x8*)pal1;

    auto body = [&](const char* bb) {
#pragma unroll
        for (int c = 0; c < 8; c++) {
            bf16x8 bh = *(const bf16x8*)(bb + c * 1024 + lane * 16);
            bf16x8 bl = *(const bf16x8*)(bb + 8192 + c * 1024 + lane * 16);
            acc0[c] = __builtin_amdgcn_mfma_f32_16x16x32_bf16(ah0, bh, acc0[c], 0, 0, 0);
            acc1[c] = __builtin_amdgcn_mfma_f32_16x16x32_bf16(ah1, bh, acc1[c], 0, 0, 0);
            acc0[c] = __builtin_amdgcn_mfma_f32_16x16x32_bf16(ah0, bl, acc0[c], 0, 0, 0);
            acc1[c] = __builtin_amdgcn_mfma_f32_16x16x32_bf16(ah1, bl, acc1[c], 0, 0, 0);
            acc0[c] = __builtin_amdgcn_mfma_f32_16x16x32_bf16(al0, bh, acc0[c], 0, 0, 0);
            acc1[c] = __builtin_amdgcn_mfma_f32_16x16x32_bf16(al1, bh, acc1[c], 0, 0, 0);
        }
    };

    stage(0, 0);
    __syncthreads();
    for (int kt = 0; kt < NKT - 1; ++kt) {
        stage(kt + 1, (kt + 1) & 1);
        bf16x8 nah0 = *(const bf16x8*)(pah0 + (kt + 1) * 32);
        bf16x8 nal0 = *(const bf16x8*)(pal0 + (kt + 1) * 32);
        bf16x8 nah1 = *(const bf16x8*)(pah1 + (kt + 1) * 32);
        bf16x8 nal1 = *(const bf16x8*)(pal1 + (kt + 1) * 32);
        body(&smem[0][0] + (kt & 1) * 16384);
        __syncthreads();
        ah0 = nah0; al0 = nal0; ah1 = nah1; al1 = nal1;
    }
    body(&smem[0][0] + ((NKT - 1) & 1) * 16384);

    const int crow0 = row_base + (lane >> 4) * 4;  // frag0 rows; frag1 = +16
    const int col15 = lane & 15;
#pragma unroll
    for (int c = 0; c < 8; c++)
#pragma unroll
        for (int r = 0; r < 4; r++) {
            int r0 = crow0 + r, r1 = r0 + 16;
            int cc = (colt0 + c) * 16 + col15;
            if (r0 < M) Cb[(size_t)r0 * N + cc] = (bf16)acc0[c][r];
            if (r1 < M) Cb[(size_t)r1 * N + cc] = (bf16)acc1[c][r];
        }

    // fused attention coefficient dots (block's 128 cols)
    float ss0[4] = {}, sd0[4] = {}, ss1[4] = {}, sd1[4] = {};
#pragma unroll
    for (int c = 0; c < 8; c++) {
        int cw = by * 128 + c * 16 + col15;          // global column
        float was = asrc[cw];                         // asrc laid out [H*128]/[256]
        float wad = adst[cw];
#pragma unroll
        for (int r = 0; r < 4; r++) {
            ss0[r] += acc0[c][r] * was; sd0[r] += acc0[c][r] * wad;
            ss1[r] += acc1[c][r] * was; sd1[r] += acc1[c][r] * wad;
        }
    }
#pragma unroll
    for (int o = 1; o < 16; o <<= 1)
#pragma unroll
        for (int r = 0; r < 4; r++) {
            ss0[r] += __shfl_xor(ss0[r], o); sd0[r] += __shfl_xor(sd0[r], o);
            ss1[r] += __shfl_xor(ss1[r], o); sd1[r] += __shfl_xor(sd1[r], o);
        }
    if (col15 == 0) {
        if constexpr (N == 512) {        // block cols == one head: direct store
#pragma unroll
            for (int r = 0; r < 4; r++) {
                int r0 = crow0 + r, r1 = r0 + 16;
                if (r0 < M) { as_out[r0 * 4 + by] = ss0[r]; ad_out[r0 * 4 + by] = sd0[r]; }
                if (r1 < M) { as_out[r1 * 4 + by] = ss1[r]; ad_out[r1 * 4 + by] = sd1[r]; }
            }
        } else {                         // half of the single head: atomics
#pragma unroll
            for (int r = 0; r < 4; r++) {
                int r0 = crow0 + r, r1 = r0 + 16;
                if (r0 < M) { atomicAdd(&as_out[r0], ss0[r]); atomicAdd(&ad_out[r0], sd0[r]); }
                if (r1 < M) { atomicAdd(&as_out[r1], ss1[r]); atomicAdd(&ad_out[r1], sd1[r]); }
            }
        }
    }
}

// -------- layer 1 softmax + aggregate: ONE WAVE per node --------
__global__ __launch_bounds__(64) void agg1(const bf16* __restrict__ h1b,
                                           const float* __restrict__ as1,
                                           const float* __restrict__ ad1,
                                           const int* __restrict__ offs,
                                           const int* __restrict__ csr_src,
                                           const int* __restrict__ csr_eid,
                                           const float* __restrict__ b1,
                                           float* __restrict__ alpha1,
                                           bf16* __restrict__ h1eh,
                                           bf16* __restrict__ h1el) {
    const int n = blockIdx.x;
    const int lane = threadIdx.x;
    const int beg = offs[n];
    const int deg = offs[n + 1] - beg;

    __shared__ int   s_src[64];
    __shared__ float s_al[64][4];

    float4 ad4 = *(const float4*)(ad1 + n * 4);
    const float adn[4] = {ad4.x, ad4.y, ad4.z, ad4.w};

    float v0[4];
    int s0 = 0, e0 = 0;
    float mx[4] = {-3e38f, -3e38f, -3e38f, -3e38f};
    for (int idx = lane; idx < deg; idx += 64) {
        int s = csr_src[beg + idx];
        float4 a4 = *(const float4*)(as1 + s * 4);
        float v[4] = {a4.x + adn[0], a4.y + adn[1], a4.z + adn[2], a4.w + adn[3]};
#pragma unroll
        for (int h = 0; h < 4; h++) {
            v[h] = v[h] > 0.f ? v[h] : 0.2f * v[h];
            mx[h] = fmaxf(mx[h], v[h]);
        }
        if (idx == lane) {
            s0 = s; e0 = csr_eid[beg + idx];
#pragma unroll
            for (int h = 0; h < 4; h++) v0[h] = v[h];
        }
    }
#pragma unroll
    for (int o = 1; o < 64; o <<= 1)
#pragma unroll
        for (int h = 0; h < 4; h++) mx[h] = fmaxf(mx[h], __shfl_xor(mx[h], o));

    float ex0[4] = {0.f, 0.f, 0.f, 0.f};
    float ls[4] = {0.f, 0.f, 0.f, 0.f};
    if (lane < deg) {
#pragma unroll
        for (int h = 0; h < 4; h++) { ex0[h] = __expf(v0[h] - mx[h]); ls[h] = ex0[h]; }
    }
    for (int idx = lane + 64; idx < deg; idx += 64) {
        int s = csr_src[beg + idx];
        float4 a4 = *(const float4*)(as1 + s * 4);
        float v[4] = {a4.x + adn[0], a4.y + adn[1], a4.z + adn[2], a4.w + adn[3]};
#pragma unroll
        for (int h = 0; h < 4; h++) {
            v[h] = v[h] > 0.f ? v[h] : 0.2f * v[h];
            ls[h] += __expf(v[h] - mx[h]);
        }
    }
#pragma unroll
    for (int o = 1; o < 64; o <<= 1)
#pragma unroll
        for (int h = 0; h < 4; h++) ls[h] += __shfl_xor(ls[h], o);
    float rden[4];
#pragma unroll
    for (int h = 0; h < 4; h++) rden[h] = 1.f / ls[h];

    float acc[8] = {};
    const int myh = lane >> 4;
    for (int base = 0; base < deg; base += 64) {
        int idx = base + lane;
        if (idx < deg) {
            int s, e;
            float al[4];
            if (base == 0) {
                s = s0; e = e0;
#pragma unroll
                for (int h = 0; h < 4; h++) al[h] = ex0[h] * rden[h];
            } else {
                s = csr_src[beg + idx];
                e = csr_eid[beg + idx];
                float4 a4 = *(const float4*)(as1 + s * 4);
                float v[4] = {a4.x + adn[0], a4.y + adn[1], a4.z + adn[2], a4.w + adn[3]};
#pragma unroll
                for (int h = 0; h < 4; h++) {
                    v[h] = v[h] > 0.f ? v[h] : 0.2f * v[h];
                    al[h] = __expf(v[h] - mx[h]) * rden[h];
                }
            }
            s_src[lane] = s;
#pragma unroll
            for (int h = 0; h < 4; h++) s_al[lane][h] = al[h];
            *(float4*)(alpha1 + (size_t)e * 4) = make_float4(al[0], al[1], al[2], al[3]);
        }
        __syncthreads();
        int cnt = min(64, deg - base);
        for (int i = 0; i < cnt; i++) {
            int s = s_src[i];
            float a = s_al[i][myh];
            uint4 p = *(const uint4*)(h1b + (size_t)s * F1 + lane * 8);
            acc[0] += a * bflo(p.x); acc[1] += a * bfhi(p.x);
            acc[2] += a * bflo(p.y); acc[3] += a * bfhi(p.y);
            acc[4] += a * bflo(p.z); acc[5] += a * bfhi(p.z);
            acc[6] += a * bflo(p.w); acc[7] += a * bfhi(p.w);
        }
        __syncthreads();
    }
    const int c8 = lane * 8;
    float bv[8];
    *(float4*)(bv)     = *(const float4*)(b1 + c8);
    *(float4*)(bv + 4) = *(const float4*)(b1 + c8 + 4);
    union { bf16 b[8]; uint4 u; } hh, ll;
#pragma unroll
    for (int j = 0; j < 8; j++) {
        float t = acc[j] + bv[j];
        float o = t > 0.f ? t : expm1f(t);
        bf16 hb = (bf16)o;
        hh.b[j] = hb;
        ll.b[j] = (bf16)(o - (float)hb);
    }
    *(uint4*)(h1eh + (size_t)n * F1 + c8) = hh.u;
    *(uint4*)(h1el + (size_t)n * F1 + c8) = ll.u;
}

// -------- layer 2 softmax + aggregate: ONE WAVE per node --------
__global__ __launch_bounds__(64) void agg2(const bf16* __restrict__ h2b,
                                           const float* __restrict__ as2,
                                           const float* __restrict__ ad2,
                                           const int* __restrict__ offs,
                                           const int* __restrict__ csr_src,
                                           const int* __restrict__ csr_eid,
                                           const float* __restrict__ b2,
                                           float* __restrict__ alpha2,
                                           float* __restrict__ out) {
    const int n = blockIdx.x;
    const int lane = threadIdx.x;
    const int beg = offs[n];
    const int deg = offs[n + 1] - beg;

    __shared__ int   s_src[64];
    __shared__ float s_al[64];

    const float adn = ad2[n];

    float v0 = 0.f;
    int s0 = 0, e0 = 0;
    float mx = -3e38f;
    for (int idx = lane; idx < deg; idx += 64) {
        int s = csr_src[beg + idx];
        float v = as2[s] + adn;
        v = v > 0.f ? v : 0.2f * v;
        mx = fmaxf(mx, v);
        if (idx == lane) { s0 = s; e0 = csr_eid[beg + idx]; v0 = v; }
    }
#pragma unroll
    for (int o = 1; o < 64; o <<= 1) mx = fmaxf(mx, __shfl_xor(mx, o));

    float ex0 = 0.f, ls = 0.f;
    if (lane < deg) { ex0 = __expf(v0 - mx); ls = ex0; }
    for (int idx = lane + 64; idx < deg; idx += 64) {
        int s = csr_src[beg + idx];
        float v = as2[s] + adn;
        v = v > 0.f ? v : 0.2f * v;
        ls += __expf(v - mx);
    }
#pragma unroll
    for (int o = 1; o < 64; o <<= 1) ls += __shfl_xor(ls, o);
    float rden = 1.f / ls;

    float acc[4] = {};
    for (int base = 0; base < deg; base += 64) {
        int idx = base + lane;
        if (idx < deg) {
            int s, e;
            float a;
            if (base == 0) { s = s0; e = e0; a = ex0 * rden; }
            else {
                s = csr_src[beg + idx];
                e = csr_eid[beg + idx];
                float v = as2[s] + adn;
                v = v > 0.f ? v : 0.2f * v;
                a = __expf(v - mx) * rden;
            }
            s_src[lane] = s;
            s_al[lane] = a;
            alpha2[e] = a;
        }
        __syncthreads();
        int cnt = min(64, deg - base);
        for (int i = 0; i < cnt; i++) {
            int s = s_src[i];
            float a = s_al[i];
            uint2 p = *(const uint2*)(h2b + (size_t)s * F2 + lane * 4);
            acc[0] += a * bflo(p.x); acc[1] += a * bfhi(p.x);
            acc[2] += a * bflo(p.y); acc[3] += a * bfhi(p.y);
        }
        __syncthreads();
    }
    const int c4 = lane * 4;
    float4 bv = *(const float4*)(b2 + c4);
    *(float4*)(out + (size_t)n * F2 + c4) =
        make_float4(acc[0] + bv.x, acc[1] + bv.y, acc[2] + bv.z, acc[3] + bv.w);
}

// ---------------- launch ----------------
extern "C" void kernel_launch(void* const* d_in, const int* in_sizes, int n_in,
                              void* d_out, int out_size, void* d_ws, size_t ws_size,
                              hipStream_t stream) {
    const float* x      = (const float*)d_in[0];
    const int*   ei     = (const int*)d_in[1];
    const float* W1     = (const float*)d_in[2];
    const float* a_src1 = (const float*)d_in[3];
    const float* a_dst1 = (const float*)d_in[4];
    const float* b1     = (const float*)d_in[5];
    const float* W2     = (const float*)d_in[6];
    const float* a_src2 = (const float*)d_in[7];
    const float* a_dst2 = (const float*)d_in[8];
    const float* b2     = (const float*)d_in[9];

    char* ws = (char*)d_ws;
    size_t off = 0;
    auto alloc = [&](size_t bytes) -> char* {
        char* p = ws + off;
        off += (bytes + 255) & ~(size_t)255;
        return p;
    };
    bf16*  h1b  = (bf16*) alloc((size_t)NNODES * F1 * 2);   // 20.5 MB
    bf16*  h2b  = (bf16*) alloc((size_t)NNODES * F2 * 2);   // 10.2 MB
    bf16*  h1eh = (bf16*) alloc((size_t)NNODES * F1 * 2);   // 20.5 MB
    bf16*  h1el = (bf16*) alloc((size_t)NNODES * F1 * 2);   // 20.5 MB
    bf16*  Xh   = (bf16*) alloc((size_t)NNODES * F1 * 2);   // 20.5 MB
    bf16*  Xl   = (bf16*) alloc((size_t)NNODES * F1 * 2);   // 20.5 MB
    float* as1  = (float*)alloc((size_t)NNODES * 4 * 4);
    float* ad1  = (float*)alloc((size_t)NNODES * 4 * 4);
    float* as2  = (float*)alloc((size_t)NNODES * 4);
    float* ad2  = (float*)alloc((size_t)NNODES * 4);
    bf16*  W1h  = (bf16*) alloc((size_t)512 * 512 * 2);
    bf16*  W1l  = (bf16*) alloc((size_t)512 * 512 * 2);
    bf16*  W2h  = (bf16*) alloc((size_t)512 * 256 * 2);
    bf16*  W2l  = (bf16*) alloc((size_t)512 * 256 * 2);
    int*   deg  = (int*)  alloc((size_t)NNODES * 4);
    int*   offs = (int*)  alloc((size_t)(NNODES + 1) * 4);
    int*   cur  = (int*)  alloc((size_t)NNODES * 4);
    int*   csrS = (int*)  alloc((size_t)ETOT * 4);
    int*   csrE = (int*)  alloc((size_t)ETOT * 4);

    float* out2   = (float*)d_out;                      // [20000,256]
    float* alpha1 = out2 + (size_t)NNODES * F2;         // [340000,4]
    float* alpha2 = alpha1 + (size_t)ETOT * HEADS;      // [340000]

    hipMemsetAsync(deg, 0, (size_t)NNODES * 4, stream);
    hipMemsetAsync(as2, 0, (size_t)NNODES * 4, stream);
    hipMemsetAsync(ad2, 0, (size_t)NNODES * 4, stream);
    deg_count<<<(ETOT + 255) / 256, 256, 0, stream>>>(ei, deg);
    scan_deg<<<1, 1024, 0, stream>>>(deg, offs, cur);
    fill_csr<<<(ETOT + 255) / 256, 256, 0, stream>>>(ei, cur, csrS, csrE);

    swizzle_w<<<(512 * 512 / 8 + 255) / 256, 256, 0, stream>>>(W1, W1h, W1l, 512, 512);
    swizzle_w<<<(512 * 256 / 8 + 255) / 256, 256, 0, stream>>>(W2, W2h, W2l, 512, 256);
    split_f32<<<(NNODES * F1 / 8 + 255) / 256, 256, 0, stream>>>(
        x, Xh, Xl, NNODES * F1 / 8);

    gemm_fused<512, 512, 4><<<313 * 4, 128, 0, stream>>>(
        Xh, Xl, W1h, W1l, h1b, a_src1, a_dst1, as1, ad1, NNODES);
    agg1<<<NNODES, 64, 0, stream>>>(h1b, as1, ad1, offs, csrS, csrE, b1, alpha1,
                                    h1eh, h1el);

    gemm_fused<512, 256, 2><<<313 * 2, 128, 0, stream>>>(
        h1eh, h1el, W2h, W2l, h2b, a_src2, a_dst2, as2, ad2, NNODES);
    agg2<<<NNODES, 64, 0, stream>>>(h2b, as2, ad2, offs, csrS, csrE, b2, alpha2, out2);
}